// Round 16
// baseline (119.423 us; speedup 1.0000x reference)
//
#include <hip/hip_runtime.h>
#include <hip/hip_bf16.h>
#include <math.h>

typedef __attribute__((ext_vector_type(8))) short b16x8;
typedef __attribute__((ext_vector_type(4))) short b16x4;
typedef __attribute__((ext_vector_type(4))) float floatx4;
typedef __attribute__((ext_vector_type(16))) float f32x16;

constexpr int BATCH = 4, CCH = 384, NQ = 4096, NHD = 8, HDIM = 48, NK = 1024;
constexpr float SCALE_L2E = 0.14433756729740643f * 1.4426950408889634f; // 48^-0.5 * log2(e)

__device__ inline unsigned short f2bf(float f) {
    unsigned u = __builtin_bit_cast(unsigned, f);
    u += 0x7fffu + ((u >> 16) & 1u);
    return (unsigned short)(u >> 16);
}

__device__ __forceinline__ void g2lds16(const void* g, void* l) {
    __builtin_amdgcn_global_load_lds(
        (const __attribute__((address_space(1))) unsigned int*)g,
        (__attribute__((address_space(3))) unsigned int*)l, 16, 0, 0);
}

// ---------------------------------------------------------------------------
// PREP (one dispatch): weight cvt fp32->bf16 + x transpose.
// ---------------------------------------------------------------------------
__global__ void prep_kern(const float* __restrict__ Wq, const float* __restrict__ Wk,
                          const float* __restrict__ Wv, const float* __restrict__ Wsr,
                          const float* __restrict__ Wp, const float* __restrict__ x,
                          short* __restrict__ WqB, short* __restrict__ WkvB,
                          short* __restrict__ WsrB, short* __restrict__ WpB,
                          short* __restrict__ xT) {
    int job = blockIdx.y;
    if (job == 5) {   // x [B][384][4096] f32 -> xT [B][4096][384] bf16
        for (int i = blockIdx.x * 256 + threadIdx.x; i < BATCH * 4096 * 48;
             i += 576 * 256) {
            int b = i / (4096 * 48);
            int rem = i - b * (4096 * 48);
            int c8 = rem / 4096, s = rem - c8 * 4096;
            b16x8 pk;
            #pragma unroll
            for (int e = 0; e < 8; e++)
                pk[e] = (short)f2bf(x[((size_t)b * CCH + c8 * 8 + e) * NQ + s]);
            *(b16x8*)(xT + ((size_t)b * NQ + s) * CCH + c8 * 8) = pk;
        }
        return;
    }
    if (job == 3) {   // WsrB[o][ (r&3)*384 + (r>>2) ] = Wsr[o][r],  r = c*4+p
        for (int i = blockIdx.x * 256 + threadIdx.x; i < 589824; i += gridDim.x * 256) {
            int o = i / 1536, r = i - o * 1536;
            WsrB[o * 1536 + (r & 3) * 384 + (r >> 2)] = (short)f2bf(Wsr[i]);
        }
        return;
    }
    const float* src; short* dst;
    if (job == 0)      { src = Wq;  dst = WqB; }
    else if (job == 1) { src = Wk;  dst = WkvB; }
    else if (job == 2) { src = Wv;  dst = WkvB + 147456; }
    else               { src = Wp;  dst = WpB; }
    for (int i = blockIdx.x * 256 + threadIdx.x; i < 147456; i += gridDim.x * 256)
        dst[i] = (short)f2bf(src[i]);
}

// ---------------------------------------------------------------------------
// FUSED conv+Q GEMM (480 blocks).  id<24 per batch: SR-conv (im2col, K=1536,
// +bsr) -> xsrT.  Else: Q (K=384) -> qT.
// ---------------------------------------------------------------------------
__global__ __launch_bounds__(256, 2) void fused_gemm1(
    const short* __restrict__ WsrB, const short* __restrict__ WqB,
    const short* __restrict__ xT, const float* __restrict__ bsr,
    short* __restrict__ xsrT, short* __restrict__ qTb)
{
    __shared__ short At[128 * 64];
    __shared__ short Bt[128 * 64];
    const int b = blockIdx.z;
    const int id = blockIdx.x;
    const bool conv = id < 24;
    const int sx = conv ? (id & 7) : ((id - 24) & 31);
    const int oy = conv ? (id >> 3) : ((id - 24) >> 5);
    const int Ks = conv ? 1536 : 384;
    const int S  = conv ? NK : NQ;
    const short* A = conv ? WsrB : WqB;
    short* Yt = conv ? xsrT : qTb;
    const int o0 = oy * 128, s0 = sx * 128;
    const int t = threadIdx.x, wave = t >> 6, lane = t & 63, g = lane >> 4, li = lane & 15;
    const int wr = wave >> 1, wc = wave & 1;
    floatx4 acc[4][4] = {};
    const short* Bbase = xT + (size_t)b * NQ * CCH;

    for (int k0 = 0; k0 < Ks; k0 += 64) {
        __syncthreads();
        #pragma unroll
        for (int it = 0; it < 4; it++) {
            int task = it * 256 + t;
            int row = task >> 3, ch = task & 7;
            int cont = ch ^ (row & 7);
            g2lds16(A + (size_t)(o0 + row) * Ks + k0 + cont * 8, At + task * 8);
        }
        #pragma unroll
        for (int it = 0; it < 4; it++) {
            int task = it * 256 + t;
            int row = task >> 3, ch = task & 7;
            int cont = ch ^ (row & 7);
            if (conv) {
                int ssr = s0 + row;
                int hs = ssr >> 5, wsv = ssr & 31;
                int k = k0 + cont * 8;
                int p = k / 384, coff = k - p * 384;
                g2lds16(Bbase + (size_t)((2 * hs + (p >> 1)) * 64 + 2 * wsv + (p & 1)) * 384 + coff,
                        Bt + task * 8);
            } else {
                g2lds16(Bbase + (size_t)(s0 + row) * 384 + k0 + cont * 8, Bt + task * 8);
            }
        }
        __syncthreads();
        #pragma unroll
        for (int kk = 0; kk < 2; kk++) {
            b16x8 af[4], bf[4];
            #pragma unroll
            for (int mi = 0; mi < 4; mi++) {
                int r = wr * 64 + mi * 16 + li;
                af[mi] = *(const b16x8*)(At + r * 64 + (((kk * 4 + g) ^ (r & 7)) * 8));
            }
            #pragma unroll
            for (int nf = 0; nf < 4; nf++) {
                int r = wc * 64 + nf * 16 + li;
                bf[nf] = *(const b16x8*)(Bt + r * 64 + (((kk * 4 + g) ^ (r & 7)) * 8));
            }
            #pragma unroll
            for (int mi = 0; mi < 4; mi++)
                #pragma unroll
                for (int nf = 0; nf < 4; nf++)
                    acc[mi][nf] = __builtin_amdgcn_mfma_f32_16x16x32_bf16(af[mi], bf[nf], acc[mi][nf], 0, 0, 0);
        }
    }

    #pragma unroll
    for (int mi = 0; mi < 4; mi++) {
        #pragma unroll
        for (int nf = 0; nf < 4; nf++) {
            int o = o0 + wr * 64 + mi * 16 + g * 4;
            int s = s0 + wc * 64 + nf * 16 + li;
            b16x4 pk;
            #pragma unroll
            for (int j = 0; j < 4; j++) {
                float v = acc[mi][nf][j];
                if (conv) v += bsr[o + j];
                pk[j] = (short)f2bf(v);
            }
            *(b16x4*)(Yt + ((size_t)b * S + s) * CCH + o) = pk;
        }
    }
}

// ---------------------------------------------------------------------------
// KV GEMM (K=384, from xsrT): o<384 -> k (+pos, *SCALE_L2E) -> kT[m][c];
// o>=384 -> v -> vC[c][m] channel-major.
// ---------------------------------------------------------------------------
__global__ __launch_bounds__(256, 2) void kv_gemm(
    const short* __restrict__ WkvB, const short* __restrict__ xsrT,
    const float* __restrict__ relh, const float* __restrict__ relw,
    short* __restrict__ kTb, short* __restrict__ vCb)
{
    __shared__ short At[128 * 64];
    __shared__ short Bt[128 * 64];
    const int b = blockIdx.z, o0 = blockIdx.y * 128, s0 = blockIdx.x * 128;
    const int t = threadIdx.x, wave = t >> 6, lane = t & 63, g = lane >> 4, li = lane & 15;
    const int wr = wave >> 1, wc = wave & 1;
    floatx4 acc[4][4] = {};
    const short* Bbase = xsrT + (size_t)b * NK * CCH;

    for (int k0 = 0; k0 < 384; k0 += 64) {
        __syncthreads();
        #pragma unroll
        for (int it = 0; it < 4; it++) {
            int task = it * 256 + t;
            int row = task >> 3, ch = task & 7;
            int cont = ch ^ (row & 7);
            g2lds16(WkvB + (size_t)(o0 + row) * 384 + k0 + cont * 8, At + task * 8);
        }
        #pragma unroll
        for (int it = 0; it < 4; it++) {
            int task = it * 256 + t;
            int row = task >> 3, ch = task & 7;
            int cont = ch ^ (row & 7);
            g2lds16(Bbase + (size_t)(s0 + row) * 384 + k0 + cont * 8, Bt + task * 8);
        }
        __syncthreads();
        #pragma unroll
        for (int kk = 0; kk < 2; kk++) {
            b16x8 af[4], bf[4];
            #pragma unroll
            for (int mi = 0; mi < 4; mi++) {
                int r = wr * 64 + mi * 16 + li;
                af[mi] = *(const b16x8*)(At + r * 64 + (((kk * 4 + g) ^ (r & 7)) * 8));
            }
            #pragma unroll
            for (int nf = 0; nf < 4; nf++) {
                int r = wc * 64 + nf * 16 + li;
                bf[nf] = *(const b16x8*)(Bt + r * 64 + (((kk * 4 + g) ^ (r & 7)) * 8));
            }
            #pragma unroll
            for (int mi = 0; mi < 4; mi++)
                #pragma unroll
                for (int nf = 0; nf < 4; nf++)
                    acc[mi][nf] = __builtin_amdgcn_mfma_f32_16x16x32_bf16(af[mi], bf[nf], acc[mi][nf], 0, 0, 0);
        }
    }

    #pragma unroll
    for (int mi = 0; mi < 4; mi++) {
        #pragma unroll
        for (int nf = 0; nf < 4; nf++) {
            int o = o0 + wr * 64 + mi * 16 + g * 4;
            int s = s0 + wc * 64 + nf * 16 + li;
            if (o0 < 384) {
                int hs = s >> 5, wsv = s & 31;
                b16x4 pk;
                #pragma unroll
                for (int j = 0; j < 4; j++)
                    pk[j] = (short)f2bf((acc[mi][nf][j] + relh[(o + j) * 32 + wsv]
                                         + relw[(o + j) * 32 + hs]) * SCALE_L2E);
                *(b16x4*)(kTb + ((size_t)b * NK + s) * CCH + o) = pk;
            } else {
                #pragma unroll
                for (int j = 0; j < 4; j++)
                    vCb[((size_t)b * CCH + (o - 384 + j)) * NK + s] = (short)f2bf(acc[mi][nf][j]);
            }
        }
    }
}

// ---------------------------------------------------------------------------
// P projection GEMM: out[o][s] f32 = sum_k Wp[o][k] * attT[s][k] + bp[o].
// ---------------------------------------------------------------------------
__global__ __launch_bounds__(256, 2) void p_gemm(
    const short* __restrict__ A, const short* __restrict__ Bm,
    float* __restrict__ Yf, const float* __restrict__ bias)
{
    __shared__ short At[128 * 64];
    __shared__ short Bt[128 * 64];
    const int b = blockIdx.z, o0 = blockIdx.y * 128, s0 = blockIdx.x * 128;
    const int t = threadIdx.x, wave = t >> 6, lane = t & 63, g = lane >> 4, li = lane & 15;
    const int wr = wave >> 1, wc = wave & 1;
    floatx4 acc[4][4] = {};
    const short* Bbase = Bm + (size_t)b * NQ * CCH;

    for (int k0 = 0; k0 < 384; k0 += 64) {
        __syncthreads();
        #pragma unroll
        for (int it = 0; it < 4; it++) {
            int task = it * 256 + t;
            int row = task >> 3, ch = task & 7;
            int cont = ch ^ (row & 7);
            g2lds16(A + (size_t)(o0 + row) * 384 + k0 + cont * 8, At + task * 8);
        }
        #pragma unroll
        for (int it = 0; it < 4; it++) {
            int task = it * 256 + t;
            int row = task >> 3, ch = task & 7;
            int cont = ch ^ (row & 7);
            g2lds16(Bbase + (size_t)(s0 + row) * 384 + k0 + cont * 8, Bt + task * 8);
        }
        __syncthreads();
        #pragma unroll
        for (int kk = 0; kk < 2; kk++) {
            b16x8 af[4], bf[4];
            #pragma unroll
            for (int mi = 0; mi < 4; mi++) {
                int r = wr * 64 + mi * 16 + li;
                af[mi] = *(const b16x8*)(At + r * 64 + (((kk * 4 + g) ^ (r & 7)) * 8));
            }
            #pragma unroll
            for (int nf = 0; nf < 4; nf++) {
                int r = wc * 64 + nf * 16 + li;
                bf[nf] = *(const b16x8*)(Bt + r * 64 + (((kk * 4 + g) ^ (r & 7)) * 8));
            }
            #pragma unroll
            for (int mi = 0; mi < 4; mi++)
                #pragma unroll
                for (int nf = 0; nf < 4; nf++)
                    acc[mi][nf] = __builtin_amdgcn_mfma_f32_16x16x32_bf16(af[mi], bf[nf], acc[mi][nf], 0, 0, 0);
        }
    }

    #pragma unroll
    for (int mi = 0; mi < 4; mi++) {
        #pragma unroll
        for (int nf = 0; nf < 4; nf++) {
            int o = o0 + wr * 64 + mi * 16 + g * 4;
            int s = s0 + wc * 64 + nf * 16 + li;
            #pragma unroll
            for (int j = 0; j < 4; j++)
                Yf[((size_t)b * CCH + o + j) * (size_t)NQ + s] = acc[mi][nf][j] + bias[o + j];
        }
    }
}

// ---------------------------------------------------------------------------
// Flash attention v10: QBLK 32/wave (round-12 compute structure) + 3-buffer
// counted-vmcnt pipeline (round-15 sync structure).  1024 blocks, 42 KB LDS
// -> 3 blocks/CU -> ~3 waves/SIMD for latency hiding.  One raw s_barrier per
// tile, never vmcnt(0) in the main loop.
// ---------------------------------------------------------------------------
__global__ __launch_bounds__(256, 3) void attn_kern(
    const short* __restrict__ qT, const short* __restrict__ kT,
    const short* __restrict__ vC, short* __restrict__ attT)
{
    __shared__ short Kl[3][6 * 64 * 8];   // [buf][d-chunk 0..5][row][8]
    __shared__ short Vl[3][8 * 64 * 8];   // [buf][key-chunk 0..7][d-row][8]
    const int wgid = blockIdx.x;
    const int nid = (wgid & 7) * 128 + (wgid >> 3);    // XCD swizzle (1024 = 8*128)
    const int qt = nid & 31, hh = (nid >> 5) & 7, b = nid >> 8;
    const int t = threadIdx.x, wave = t >> 6, lane = t & 63;
    const int h = lane >> 5, c = lane & 31;
    const int n0 = qt * 128 + wave * 32;

    const short* qp = qT + (size_t)b * NQ * CCH + hh * HDIM;
    const short* kp = kT + (size_t)b * NK * CCH + hh * HDIM;
    const short* vp = vC + ((size_t)b * CCH + hh * HDIM) * NK;

    // init V pad rows 48..63 of all 3 buffers: row 48 = 1.0 (l-col), rest 0
    for (int i = t; i < 384; i += 256) {          // 3 bufs x 8 chunks x 16 rows
        int bufi = i >> 7, rem = i & 127;
        int ch = rem >> 4, row = 48 + (rem & 15);
        b16x8 val = {};
        if (row == 48)
            #pragma unroll
            for (int e = 0; e < 8; e++) val[e] = (short)0x3F80;
        *(b16x8*)(&Vl[bufi][(ch * 64 + row) * 8]) = val;
    }
    asm volatile("s_waitcnt lgkmcnt(0)" ::: "memory");  // pad writes retired

    // Q B-frags (persist): lane holds q = c, d = dc*16 + h*8 + e
    b16x8 qf[3];
    #pragma unroll
    for (int dc = 0; dc < 3; dc++)
        qf[dc] = *(const b16x8*)(qp + (size_t)(n0 + c) * CCH + dc * 16 + h * 8);
    asm volatile("s_waitcnt vmcnt(0)" ::: "memory");    // qf resident; clean counter

    // hoisted staging geometry (tile-invariant)
    const int rowS = t & 63;
    const int chA = t >> 6;                        // == wave, 0..3
    const int keyS = (rowS & 51) | ((rowS & 4) << 1) | ((rowS & 8) >> 1);
    const short* ksrcA = kp + (size_t)keyS * CCH + chA * 8;
    const bool  kvalB = (chA + 4) < 6;             // wave-uniform: waves 0,1
    const bool  vval  = rowS < 48;
    const short* vsrcA = vp + (size_t)rowS * NK + chA * 8;
    const int taskA8 = t * 8, taskB8 = (t + 256) * 8;

    auto stage = [&](int m0, int bi) {
        size_t koff = (size_t)m0 * CCH;
        g2lds16(ksrcA + koff, &Kl[bi][taskA8]);                    // 1 inst, all waves
        if (kvalB) g2lds16(ksrcA + koff + 32, &Kl[bi][taskB8]);    // +1, waves 0,1
        if (vval) {                                                // masked, still issued
            g2lds16(vsrcA + m0, &Vl[bi][taskA8]);                  // +1
            g2lds16(vsrcA + m0 + 32, &Vl[bi][taskB8]);             // +1
        }
    };

    f32x16 O[2] = {};          // [dblock];  O[1] col c=16 accumulates l

    stage(0, 0);
    stage(64, 1);
    int cur = 0;
    for (int tt = 0; tt < 16; ++tt) {
        // wait for tile tt's loads only (tt+1's stay in flight)
        if (tt < 15) {
            if (wave < 2) asm volatile("s_waitcnt vmcnt(4)" ::: "memory");
            else          asm volatile("s_waitcnt vmcnt(3)" ::: "memory");
        } else {
            asm volatile("s_waitcnt vmcnt(0)" ::: "memory");
        }
        __builtin_amdgcn_s_barrier();
        const short* Kb = Kl[cur];
        const short* Vb = Vl[cur];
        #pragma unroll
        for (int kb = 0; kb < 2; kb++) {
            b16x8 kf[3];
            #pragma unroll
            for (int dc = 0; dc < 3; dc++)
                kf[dc] = *(const b16x8*)(Kb + (((dc * 2 + h) * 64) + kb * 32 + c) * 8);
            f32x16 s = {};
            __builtin_amdgcn_s_setprio(1);
            #pragma unroll
            for (int dc = 0; dc < 3; dc++)
                s = __builtin_amdgcn_mfma_f32_32x32x16_bf16(kf[dc], qf[dc], s, 0, 0, 0);
            __builtin_amdgcn_s_setprio(0);
            float p[16];
            #pragma unroll
            for (int r = 0; r < 16; r++)
                p[r] = __builtin_amdgcn_exp2f(s[r]);
            b16x8 pfrag[2];
            #pragma unroll
            for (int kk = 0; kk < 2; kk++) {
                union { unsigned u[4]; b16x8 v; } w;
                #pragma unroll
                for (int wd = 0; wd < 4; wd++)
                    asm("v_cvt_pk_bf16_f32 %0, %1, %2"
                        : "=v"(w.u[wd])
                        : "v"(p[kk * 8 + wd * 2]), "v"(p[kk * 8 + wd * 2 + 1]));
                pfrag[kk] = w.v;
            }
            __builtin_amdgcn_s_setprio(1);
            #pragma unroll
            for (int kk = 0; kk < 2; kk++)
                #pragma unroll
                for (int db = 0; db < 2; db++) {
                    b16x8 vf = *(const b16x8*)(Vb + (((kb * 4 + kk * 2 + h) * 64) + db * 32 + c) * 8);
                    O[db] = __builtin_amdgcn_mfma_f32_32x32x16_bf16(pfrag[kk], vf, O[db], 0, 0, 0);
                }
            __builtin_amdgcn_s_setprio(0);
        }
        // prefetch tile tt+2 into buffer (cur+2)%3 (safe: all waves passed
        // barrier tt, i.e. finished reading buf (tt-1)%3 == (cur+2)%3)
        if (tt < 14) {
            int nb = cur + 2; if (nb >= 3) nb -= 3;
            stage((tt + 2) * 64, nb);
        }
        cur = (cur == 2) ? 0 : cur + 1;
    }

    __syncthreads();   // full drain: all waves done reading V before overlay
    // l[q-slot r] lives in lane (h, c=16) at O[1][r]; wave-private bounce
    short* Olw = ((short*)Vl) + wave * 2048;   // 4 KB per wave
    #pragma unroll
    for (int r = 0; r < 16; r++) {
        int qrow = (r & 3) + 8 * (r >> 2) + 4 * h;
        float lr = __shfl(O[1][r], (lane & 32) | 16);
        float iq = 1.0f / lr;
        #pragma unroll
        for (int db = 0; db < 2; db++) {
            int d = db * 32 + c;
            if (d < 48)
                Olw[qrow * 64 + (((d >> 3) ^ (qrow & 7)) * 8) + (d & 7)] =
                    (short)f2bf(O[db][r] * iq);
        }
    }
    #pragma unroll
    for (int it = 0; it < 4; it++) {
        int idx = it * 64 + lane;
        int row = idx >> 3, c8 = idx & 7;
        if (c8 < 6) {
            b16x8 val = *(const b16x8*)(Olw + row * 64 + ((c8 ^ (row & 7)) * 8));
            *(b16x8*)(attT + ((size_t)b * NQ + n0 + row) * CCH + hh * HDIM + c8 * 8) = val;
        }
    }
}

// ---------------------------------------------------------------------------
extern "C" void kernel_launch(void* const* d_in, const int* in_sizes, int n_in,
                              void* d_out, int out_size, void* d_ws, size_t ws_size,
                              hipStream_t stream) {
    const float* x    = (const float*)d_in[0];
    const float* Wq   = (const float*)d_in[1];
    const float* Wk   = (const float*)d_in[2];
    const float* Wv   = (const float*)d_in[3];
    const float* Wsr  = (const float*)d_in[4];
    const float* bsr  = (const float*)d_in[5];
    const float* Wp   = (const float*)d_in[6];
    const float* bp   = (const float*)d_in[7];
    const float* relh = (const float*)d_in[8];
    const float* relw = (const float*)d_in[9];
    float* out = (float*)d_out;

    short* ws = (short*)d_ws;
    size_t off = 0;
    auto alloc = [&](size_t n) { short* p = ws + off; off += n; return p; };
    short* WqB  = alloc(147456);
    short* WkvB = alloc(294912);
    short* WsrB = alloc(589824);
    short* WpB  = alloc(147456);
    short* xT   = alloc((size_t)BATCH * NQ * CCH);
    short* xsrT = alloc((size_t)BATCH * NK * CCH);
    short* qTb  = alloc((size_t)BATCH * NQ * CCH);
    short* kTb  = alloc((size_t)BATCH * NK * CCH);
    short* vCb  = alloc((size_t)BATCH * CCH * NK);
    short* attT = alloc((size_t)BATCH * NQ * CCH);

    prep_kern<<<dim3(576, 6), 256, 0, stream>>>(Wq, Wk, Wv, Wsr, Wp, x,
                                                WqB, WkvB, WsrB, WpB, xT);
    fused_gemm1<<<dim3(120, 1, BATCH), 256, 0, stream>>>(WsrB, WqB, xT, bsr, xsrT, qTb);
    kv_gemm<<<dim3(8, 6, BATCH), 256, 0, stream>>>(WkvB, xsrT, relh, relw, kTb, vCb);
    attn_kern<<<dim3(1024), 256, 0, stream>>>(qTb, kTb, vCb, attT);
    p_gemm<<<dim3(32, 3, BATCH), 256, 0, stream>>>(WpB, attT, out, bp);
}

// Round 17
// 111.562 us; speedup vs baseline: 1.0705x; 1.0705x over previous
//
#include <hip/hip_runtime.h>
#include <hip/hip_bf16.h>
#include <math.h>

typedef __attribute__((ext_vector_type(8))) short b16x8;
typedef __attribute__((ext_vector_type(4))) short b16x4;
typedef __attribute__((ext_vector_type(4))) float floatx4;
typedef __attribute__((ext_vector_type(16))) float f32x16;

constexpr int BATCH = 4, CCH = 384, NQ = 4096, NHD = 8, HDIM = 48, NK = 1024;
constexpr float SCALE_L2E = 0.14433756729740643f * 1.4426950408889634f; // 48^-0.5 * log2(e)

__device__ inline unsigned short f2bf(float f) {
    unsigned u = __builtin_bit_cast(unsigned, f);
    u += 0x7fffu + ((u >> 16) & 1u);
    return (unsigned short)(u >> 16);
}

__device__ __forceinline__ void g2lds16(const void* g, void* l) {
    __builtin_amdgcn_global_load_lds(
        (const __attribute__((address_space(1))) unsigned int*)g,
        (__attribute__((address_space(3))) unsigned int*)l, 16, 0, 0);
}

// ---------------------------------------------------------------------------
// PREP (one dispatch): weight cvt fp32->bf16 + x transpose.
// ---------------------------------------------------------------------------
__global__ void prep_kern(const float* __restrict__ Wq, const float* __restrict__ Wk,
                          const float* __restrict__ Wv, const float* __restrict__ Wsr,
                          const float* __restrict__ Wp, const float* __restrict__ x,
                          short* __restrict__ WqB, short* __restrict__ WkvB,
                          short* __restrict__ WsrB, short* __restrict__ WpB,
                          short* __restrict__ xT) {
    int job = blockIdx.y;
    if (job == 5) {   // x [B][384][4096] f32 -> xT [B][4096][384] bf16
        for (int i = blockIdx.x * 256 + threadIdx.x; i < BATCH * 4096 * 48;
             i += 576 * 256) {
            int b = i / (4096 * 48);
            int rem = i - b * (4096 * 48);
            int c8 = rem / 4096, s = rem - c8 * 4096;
            b16x8 pk;
            #pragma unroll
            for (int e = 0; e < 8; e++)
                pk[e] = (short)f2bf(x[((size_t)b * CCH + c8 * 8 + e) * NQ + s]);
            *(b16x8*)(xT + ((size_t)b * NQ + s) * CCH + c8 * 8) = pk;
        }
        return;
    }
    if (job == 3) {   // WsrB[o][ (r&3)*384 + (r>>2) ] = Wsr[o][r],  r = c*4+p
        for (int i = blockIdx.x * 256 + threadIdx.x; i < 589824; i += gridDim.x * 256) {
            int o = i / 1536, r = i - o * 1536;
            WsrB[o * 1536 + (r & 3) * 384 + (r >> 2)] = (short)f2bf(Wsr[i]);
        }
        return;
    }
    const float* src; short* dst;
    if (job == 0)      { src = Wq;  dst = WqB; }
    else if (job == 1) { src = Wk;  dst = WkvB; }
    else if (job == 2) { src = Wv;  dst = WkvB + 147456; }
    else               { src = Wp;  dst = WpB; }
    for (int i = blockIdx.x * 256 + threadIdx.x; i < 147456; i += gridDim.x * 256)
        dst[i] = (short)f2bf(src[i]);
}

// ---------------------------------------------------------------------------
// FUSED conv+Q GEMM (480 blocks).  id<24 per batch: SR-conv (im2col, K=1536,
// +bsr) -> xsrT.  Else: Q (K=384) -> qT.
// ---------------------------------------------------------------------------
__global__ __launch_bounds__(256, 2) void fused_gemm1(
    const short* __restrict__ WsrB, const short* __restrict__ WqB,
    const short* __restrict__ xT, const float* __restrict__ bsr,
    short* __restrict__ xsrT, short* __restrict__ qTb)
{
    __shared__ short At[128 * 64];
    __shared__ short Bt[128 * 64];
    const int b = blockIdx.z;
    const int id = blockIdx.x;
    const bool conv = id < 24;
    const int sx = conv ? (id & 7) : ((id - 24) & 31);
    const int oy = conv ? (id >> 3) : ((id - 24) >> 5);
    const int Ks = conv ? 1536 : 384;
    const int S  = conv ? NK : NQ;
    const short* A = conv ? WsrB : WqB;
    short* Yt = conv ? xsrT : qTb;
    const int o0 = oy * 128, s0 = sx * 128;
    const int t = threadIdx.x, wave = t >> 6, lane = t & 63, g = lane >> 4, li = lane & 15;
    const int wr = wave >> 1, wc = wave & 1;
    floatx4 acc[4][4] = {};
    const short* Bbase = xT + (size_t)b * NQ * CCH;

    for (int k0 = 0; k0 < Ks; k0 += 64) {
        __syncthreads();
        #pragma unroll
        for (int it = 0; it < 4; it++) {
            int task = it * 256 + t;
            int row = task >> 3, ch = task & 7;
            int cont = ch ^ (row & 7);
            g2lds16(A + (size_t)(o0 + row) * Ks + k0 + cont * 8, At + task * 8);
        }
        #pragma unroll
        for (int it = 0; it < 4; it++) {
            int task = it * 256 + t;
            int row = task >> 3, ch = task & 7;
            int cont = ch ^ (row & 7);
            if (conv) {
                int ssr = s0 + row;
                int hs = ssr >> 5, wsv = ssr & 31;
                int k = k0 + cont * 8;
                int p = k / 384, coff = k - p * 384;
                g2lds16(Bbase + (size_t)((2 * hs + (p >> 1)) * 64 + 2 * wsv + (p & 1)) * 384 + coff,
                        Bt + task * 8);
            } else {
                g2lds16(Bbase + (size_t)(s0 + row) * 384 + k0 + cont * 8, Bt + task * 8);
            }
        }
        __syncthreads();
        #pragma unroll
        for (int kk = 0; kk < 2; kk++) {
            b16x8 af[4], bf[4];
            #pragma unroll
            for (int mi = 0; mi < 4; mi++) {
                int r = wr * 64 + mi * 16 + li;
                af[mi] = *(const b16x8*)(At + r * 64 + (((kk * 4 + g) ^ (r & 7)) * 8));
            }
            #pragma unroll
            for (int nf = 0; nf < 4; nf++) {
                int r = wc * 64 + nf * 16 + li;
                bf[nf] = *(const b16x8*)(Bt + r * 64 + (((kk * 4 + g) ^ (r & 7)) * 8));
            }
            #pragma unroll
            for (int mi = 0; mi < 4; mi++)
                #pragma unroll
                for (int nf = 0; nf < 4; nf++)
                    acc[mi][nf] = __builtin_amdgcn_mfma_f32_16x16x32_bf16(af[mi], bf[nf], acc[mi][nf], 0, 0, 0);
        }
    }

    #pragma unroll
    for (int mi = 0; mi < 4; mi++) {
        #pragma unroll
        for (int nf = 0; nf < 4; nf++) {
            int o = o0 + wr * 64 + mi * 16 + g * 4;
            int s = s0 + wc * 64 + nf * 16 + li;
            b16x4 pk;
            #pragma unroll
            for (int j = 0; j < 4; j++) {
                float v = acc[mi][nf][j];
                if (conv) v += bsr[o + j];
                pk[j] = (short)f2bf(v);
            }
            *(b16x4*)(Yt + ((size_t)b * S + s) * CCH + o) = pk;
        }
    }
}

// ---------------------------------------------------------------------------
// KV GEMM (K=384, from xsrT): o<384 -> k (+pos, *SCALE_L2E) -> kT[m][c];
// o>=384 -> v -> vC[c][m] channel-major.
// ---------------------------------------------------------------------------
__global__ __launch_bounds__(256, 2) void kv_gemm(
    const short* __restrict__ WkvB, const short* __restrict__ xsrT,
    const float* __restrict__ relh, const float* __restrict__ relw,
    short* __restrict__ kTb, short* __restrict__ vCb)
{
    __shared__ short At[128 * 64];
    __shared__ short Bt[128 * 64];
    const int b = blockIdx.z, o0 = blockIdx.y * 128, s0 = blockIdx.x * 128;
    const int t = threadIdx.x, wave = t >> 6, lane = t & 63, g = lane >> 4, li = lane & 15;
    const int wr = wave >> 1, wc = wave & 1;
    floatx4 acc[4][4] = {};
    const short* Bbase = xsrT + (size_t)b * NK * CCH;

    for (int k0 = 0; k0 < 384; k0 += 64) {
        __syncthreads();
        #pragma unroll
        for (int it = 0; it < 4; it++) {
            int task = it * 256 + t;
            int row = task >> 3, ch = task & 7;
            int cont = ch ^ (row & 7);
            g2lds16(WkvB + (size_t)(o0 + row) * 384 + k0 + cont * 8, At + task * 8);
        }
        #pragma unroll
        for (int it = 0; it < 4; it++) {
            int task = it * 256 + t;
            int row = task >> 3, ch = task & 7;
            int cont = ch ^ (row & 7);
            g2lds16(Bbase + (size_t)(s0 + row) * 384 + k0 + cont * 8, Bt + task * 8);
        }
        __syncthreads();
        #pragma unroll
        for (int kk = 0; kk < 2; kk++) {
            b16x8 af[4], bf[4];
            #pragma unroll
            for (int mi = 0; mi < 4; mi++) {
                int r = wr * 64 + mi * 16 + li;
                af[mi] = *(const b16x8*)(At + r * 64 + (((kk * 4 + g) ^ (r & 7)) * 8));
            }
            #pragma unroll
            for (int nf = 0; nf < 4; nf++) {
                int r = wc * 64 + nf * 16 + li;
                bf[nf] = *(const b16x8*)(Bt + r * 64 + (((kk * 4 + g) ^ (r & 7)) * 8));
            }
            #pragma unroll
            for (int mi = 0; mi < 4; mi++)
                #pragma unroll
                for (int nf = 0; nf < 4; nf++)
                    acc[mi][nf] = __builtin_amdgcn_mfma_f32_16x16x32_bf16(af[mi], bf[nf], acc[mi][nf], 0, 0, 0);
        }
    }

    #pragma unroll
    for (int mi = 0; mi < 4; mi++) {
        #pragma unroll
        for (int nf = 0; nf < 4; nf++) {
            int o = o0 + wr * 64 + mi * 16 + g * 4;
            int s = s0 + wc * 64 + nf * 16 + li;
            if (o0 < 384) {
                int hs = s >> 5, wsv = s & 31;
                b16x4 pk;
                #pragma unroll
                for (int j = 0; j < 4; j++)
                    pk[j] = (short)f2bf((acc[mi][nf][j] + relh[(o + j) * 32 + wsv]
                                         + relw[(o + j) * 32 + hs]) * SCALE_L2E);
                *(b16x4*)(kTb + ((size_t)b * NK + s) * CCH + o) = pk;
            } else {
                #pragma unroll
                for (int j = 0; j < 4; j++)
                    vCb[((size_t)b * CCH + (o - 384 + j)) * NK + s] = (short)f2bf(acc[mi][nf][j]);
            }
        }
    }
}

// ---------------------------------------------------------------------------
// P projection GEMM: out[o][s] f32 = sum_k Wp[o][k] * attT[s][k] + bp[o].
// ---------------------------------------------------------------------------
__global__ __launch_bounds__(256, 2) void p_gemm(
    const short* __restrict__ A, const short* __restrict__ Bm,
    float* __restrict__ Yf, const float* __restrict__ bias)
{
    __shared__ short At[128 * 64];
    __shared__ short Bt[128 * 64];
    const int b = blockIdx.z, o0 = blockIdx.y * 128, s0 = blockIdx.x * 128;
    const int t = threadIdx.x, wave = t >> 6, lane = t & 63, g = lane >> 4, li = lane & 15;
    const int wr = wave >> 1, wc = wave & 1;
    floatx4 acc[4][4] = {};
    const short* Bbase = Bm + (size_t)b * NQ * CCH;

    for (int k0 = 0; k0 < 384; k0 += 64) {
        __syncthreads();
        #pragma unroll
        for (int it = 0; it < 4; it++) {
            int task = it * 256 + t;
            int row = task >> 3, ch = task & 7;
            int cont = ch ^ (row & 7);
            g2lds16(A + (size_t)(o0 + row) * 384 + k0 + cont * 8, At + task * 8);
        }
        #pragma unroll
        for (int it = 0; it < 4; it++) {
            int task = it * 256 + t;
            int row = task >> 3, ch = task & 7;
            int cont = ch ^ (row & 7);
            g2lds16(Bbase + (size_t)(s0 + row) * 384 + k0 + cont * 8, Bt + task * 8);
        }
        __syncthreads();
        #pragma unroll
        for (int kk = 0; kk < 2; kk++) {
            b16x8 af[4], bf[4];
            #pragma unroll
            for (int mi = 0; mi < 4; mi++) {
                int r = wr * 64 + mi * 16 + li;
                af[mi] = *(const b16x8*)(At + r * 64 + (((kk * 4 + g) ^ (r & 7)) * 8));
            }
            #pragma unroll
            for (int nf = 0; nf < 4; nf++) {
                int r = wc * 64 + nf * 16 + li;
                bf[nf] = *(const b16x8*)(Bt + r * 64 + (((kk * 4 + g) ^ (r & 7)) * 8));
            }
            #pragma unroll
            for (int mi = 0; mi < 4; mi++)
                #pragma unroll
                for (int nf = 0; nf < 4; nf++)
                    acc[mi][nf] = __builtin_amdgcn_mfma_f32_16x16x32_bf16(af[mi], bf[nf], acc[mi][nf], 0, 0, 0);
        }
    }

    #pragma unroll
    for (int mi = 0; mi < 4; mi++) {
        #pragma unroll
        for (int nf = 0; nf < 4; nf++) {
            int o = o0 + wr * 64 + mi * 16 + g * 4;
            int s = s0 + wc * 64 + nf * 16 + li;
            #pragma unroll
            for (int j = 0; j < 4; j++)
                Yf[((size_t)b * CCH + o + j) * (size_t)NQ + s] = acc[mi][nf][j] + bias[o + j];
        }
    }
}

// ---------------------------------------------------------------------------
// Flash attention v9 (round-15 best): counted-vmcnt pipeline (T3/T4).  3 LDS
// buffers, ONE raw s_barrier per tile, never vmcnt(0) in the main loop.
// QBLK 64/wave, 256 q/block, 512 blocks.
// ---------------------------------------------------------------------------
__global__ __launch_bounds__(256, 2) void attn_kern(
    const short* __restrict__ qT, const short* __restrict__ kT,
    const short* __restrict__ vC, short* __restrict__ attT)
{
    __shared__ short Kl[3][6 * 64 * 8];   // [buf][d-chunk 0..5][row][8]
    __shared__ short Vl[3][8 * 64 * 8];   // [buf][key-chunk 0..7][d-row][8]
    const int wgid = blockIdx.x;
    const int nid = (wgid & 7) * 64 + (wgid >> 3);     // XCD swizzle (512 = 8*64)
    const int qt = nid & 15, hh = (nid >> 4) & 7, b = nid >> 7;
    const int t = threadIdx.x, wave = t >> 6, lane = t & 63;
    const int h = lane >> 5, c = lane & 31;
    const int n0 = qt * 256 + wave * 64;

    const short* qp = qT + (size_t)b * NQ * CCH + hh * HDIM;
    const short* kp = kT + (size_t)b * NK * CCH + hh * HDIM;
    const short* vp = vC + ((size_t)b * CCH + hh * HDIM) * NK;

    // init V pad rows 48..63 of all 3 buffers: row 48 = 1.0 (l-col), rest 0
    for (int i = t; i < 384; i += 256) {          // 3 bufs x 8 chunks x 16 rows
        int bufi = i >> 7, rem = i & 127;
        int ch = rem >> 4, row = 48 + (rem & 15);
        b16x8 val = {};
        if (row == 48)
            #pragma unroll
            for (int e = 0; e < 8; e++) val[e] = (short)0x3F80;
        *(b16x8*)(&Vl[bufi][(ch * 64 + row) * 8]) = val;
    }
    asm volatile("s_waitcnt lgkmcnt(0)" ::: "memory");  // pad writes retired

    // Q B-frags (persist): lane holds q = c (per qb), d = dc*16 + h*8 + e
    b16x8 qf[2][3];
    #pragma unroll
    for (int qb = 0; qb < 2; qb++)
        #pragma unroll
        for (int dc = 0; dc < 3; dc++)
            qf[qb][dc] = *(const b16x8*)(qp + (size_t)(n0 + qb * 32 + c) * CCH + dc * 16 + h * 8);
    asm volatile("s_waitcnt vmcnt(0)" ::: "memory");    // qf resident; clean counter

    // hoisted staging geometry (tile-invariant)
    const int rowS = t & 63;
    const int chA = t >> 6;                        // == wave, 0..3
    const int keyS = (rowS & 51) | ((rowS & 4) << 1) | ((rowS & 8) >> 1);
    const short* ksrcA = kp + (size_t)keyS * CCH + chA * 8;
    const bool  kvalB = (chA + 4) < 6;             // wave-uniform: waves 0,1
    const bool  vval  = rowS < 48;
    const short* vsrcA = vp + (size_t)rowS * NK + chA * 8;
    const int taskA8 = t * 8, taskB8 = (t + 256) * 8;

    auto stage = [&](int m0, int bi) {
        size_t koff = (size_t)m0 * CCH;
        g2lds16(ksrcA + koff, &Kl[bi][taskA8]);                    // 1 inst, all waves
        if (kvalB) g2lds16(ksrcA + koff + 32, &Kl[bi][taskB8]);    // +1, waves 0,1
        if (vval) {                                                // masked, still issued
            g2lds16(vsrcA + m0, &Vl[bi][taskA8]);                  // +1
            g2lds16(vsrcA + m0 + 32, &Vl[bi][taskB8]);             // +1
        }
    };

    f32x16 O[2][2] = {};       // [qb][dblock];  O[qb][1] col c=16 accumulates l

    stage(0, 0);
    stage(64, 1);
    int cur = 0;
    for (int tt = 0; tt < 16; ++tt) {
        // wait for tile tt's loads only (tt+1's stay in flight)
        if (tt < 15) {
            if (wave < 2) asm volatile("s_waitcnt vmcnt(4)" ::: "memory");
            else          asm volatile("s_waitcnt vmcnt(3)" ::: "memory");
        } else {
            asm volatile("s_waitcnt vmcnt(0)" ::: "memory");
        }
        __builtin_amdgcn_s_barrier();
        const short* Kb = Kl[cur];
        const short* Vb = Vl[cur];
        #pragma unroll
        for (int kb = 0; kb < 2; kb++) {
            b16x8 kf[3];
            #pragma unroll
            for (int dc = 0; dc < 3; dc++)
                kf[dc] = *(const b16x8*)(Kb + (((dc * 2 + h) * 64) + kb * 32 + c) * 8);
            f32x16 s0v = {}, s1v = {};
            __builtin_amdgcn_s_setprio(1);
            #pragma unroll
            for (int dc = 0; dc < 3; dc++) {
                s0v = __builtin_amdgcn_mfma_f32_32x32x16_bf16(kf[dc], qf[0][dc], s0v, 0, 0, 0);
                s1v = __builtin_amdgcn_mfma_f32_32x32x16_bf16(kf[dc], qf[1][dc], s1v, 0, 0, 0);
            }
            __builtin_amdgcn_s_setprio(0);
            b16x8 pfrag[2][2];
            #pragma unroll
            for (int qb = 0; qb < 2; qb++) {
                float p[16];
                #pragma unroll
                for (int r = 0; r < 16; r++)
                    p[r] = __builtin_amdgcn_exp2f(qb ? s1v[r] : s0v[r]);
                #pragma unroll
                for (int kk = 0; kk < 2; kk++) {
                    union { unsigned u[4]; b16x8 v; } w;
                    #pragma unroll
                    for (int wd = 0; wd < 4; wd++)
                        asm("v_cvt_pk_bf16_f32 %0, %1, %2"
                            : "=v"(w.u[wd])
                            : "v"(p[kk * 8 + wd * 2]), "v"(p[kk * 8 + wd * 2 + 1]));
                    pfrag[qb][kk] = w.v;
                }
            }
            __builtin_amdgcn_s_setprio(1);
            #pragma unroll
            for (int kk = 0; kk < 2; kk++)
                #pragma unroll
                for (int db = 0; db < 2; db++) {
                    b16x8 vf = *(const b16x8*)(Vb + (((kb * 4 + kk * 2 + h) * 64) + db * 32 + c) * 8);
                    #pragma unroll
                    for (int qb = 0; qb < 2; qb++)
                        O[qb][db] = __builtin_amdgcn_mfma_f32_32x32x16_bf16(pfrag[qb][kk], vf, O[qb][db], 0, 0, 0);
                }
            __builtin_amdgcn_s_setprio(0);
        }
        // prefetch tile tt+2 into buffer (cur+2)%3 (all waves past tt-1 reads)
        if (tt < 14) {
            int nb = cur + 2; if (nb >= 3) nb -= 3;
            stage((tt + 2) * 64, nb);
        }
        cur = (cur == 2) ? 0 : cur + 1;
    }

    __syncthreads();   // full drain: all waves done reading V before overlay
    // l[q-slot r] lives in lane (h, c=16) at O[qb][1][r]; wave-private bounce
    short* Olw = ((short*)Vl) + wave * 2048;   // 4 KB per wave
    #pragma unroll
    for (int qb = 0; qb < 2; qb++) {
        #pragma unroll
        for (int r = 0; r < 16; r++) {
            int qrow = (r & 3) + 8 * (r >> 2) + 4 * h;
            float lr = __shfl(O[qb][1][r], (lane & 32) | 16);
            float iq = 1.0f / lr;
            #pragma unroll
            for (int db = 0; db < 2; db++) {
                int d = db * 32 + c;
                if (d < 48)
                    Olw[qrow * 64 + (((d >> 3) ^ (qrow & 7)) * 8) + (d & 7)] =
                        (short)f2bf(O[qb][db][r] * iq);
            }
        }
        #pragma unroll
        for (int it = 0; it < 4; it++) {
            int idx = it * 64 + lane;
            int row = idx >> 3, c8 = idx & 7;
            if (c8 < 6) {
                b16x8 val = *(const b16x8*)(Olw + row * 64 + ((c8 ^ (row & 7)) * 8));
                *(b16x8*)(attT + ((size_t)b * NQ + n0 + qb * 32 + row) * CCH + hh * HDIM + c8 * 8) = val;
            }
        }
    }
}

// ---------------------------------------------------------------------------
extern "C" void kernel_launch(void* const* d_in, const int* in_sizes, int n_in,
                              void* d_out, int out_size, void* d_ws, size_t ws_size,
                              hipStream_t stream) {
    const float* x    = (const float*)d_in[0];
    const float* Wq   = (const float*)d_in[1];
    const float* Wk   = (const float*)d_in[2];
    const float* Wv   = (const float*)d_in[3];
    const float* Wsr  = (const float*)d_in[4];
    const float* bsr  = (const float*)d_in[5];
    const float* Wp   = (const float*)d_in[6];
    const float* bp   = (const float*)d_in[7];
    const float* relh = (const float*)d_in[8];
    const float* relw = (const float*)d_in[9];
    float* out = (float*)d_out;

    short* ws = (short*)d_ws;
    size_t off = 0;
    auto alloc = [&](size_t n) { short* p = ws + off; off += n; return p; };
    short* WqB  = alloc(147456);
    short* WkvB = alloc(294912);
    short* WsrB = alloc(589824);
    short* WpB  = alloc(147456);
    short* xT   = alloc((size_t)BATCH * NQ * CCH);
    short* xsrT = alloc((size_t)BATCH * NK * CCH);
    short* qTb  = alloc((size_t)BATCH * NQ * CCH);
    short* kTb  = alloc((size_t)BATCH * NK * CCH);
    short* vCb  = alloc((size_t)BATCH * CCH * NK);
    short* attT = alloc((size_t)BATCH * NQ * CCH);

    prep_kern<<<dim3(576, 6), 256, 0, stream>>>(Wq, Wk, Wv, Wsr, Wp, x,
                                                WqB, WkvB, WsrB, WpB, xT);
    fused_gemm1<<<dim3(120, 1, BATCH), 256, 0, stream>>>(WsrB, WqB, xT, bsr, xsrT, qTb);
    kv_gemm<<<dim3(8, 6, BATCH), 256, 0, stream>>>(WkvB, xsrT, relh, relw, kTb, vCb);
    attn_kern<<<dim3(512), 256, 0, stream>>>(qTb, kTb, vCb, attT);
    p_gemm<<<dim3(32, 3, BATCH), 256, 0, stream>>>(WpB, attT, out, bp);
}

// Round 20
// 109.027 us; speedup vs baseline: 1.0953x; 1.0232x over previous
//
#include <hip/hip_runtime.h>
#include <hip/hip_bf16.h>
#include <math.h>

typedef __attribute__((ext_vector_type(8))) short b16x8;
typedef __attribute__((ext_vector_type(4))) short b16x4;
typedef __attribute__((ext_vector_type(4))) float floatx4;
typedef __attribute__((ext_vector_type(16))) float f32x16;

constexpr int BATCH = 4, CCH = 384, NQ = 4096, NHD = 8, HDIM = 48, NK = 1024;
constexpr float SCALE_L2E = 0.14433756729740643f * 1.4426950408889634f; // 48^-0.5 * log2(e)

__device__ inline unsigned short f2bf(float f) {
    unsigned u = __builtin_bit_cast(unsigned, f);
    u += 0x7fffu + ((u >> 16) & 1u);
    return (unsigned short)(u >> 16);
}

__device__ __forceinline__ void g2lds16(const void* g, void* l) {
    __builtin_amdgcn_global_load_lds(
        (const __attribute__((address_space(1))) unsigned int*)g,
        (__attribute__((address_space(3))) unsigned int*)l, 16, 0, 0);
}

// ---------------------------------------------------------------------------
// PREP (one dispatch): weight cvt fp32->bf16 + x transpose.
// ---------------------------------------------------------------------------
__global__ void prep_kern(const float* __restrict__ Wq, const float* __restrict__ Wk,
                          const float* __restrict__ Wv, const float* __restrict__ Wsr,
                          const float* __restrict__ Wp, const float* __restrict__ x,
                          short* __restrict__ WqB, short* __restrict__ WkvB,
                          short* __restrict__ WsrB, short* __restrict__ WpB,
                          short* __restrict__ xT) {
    int job = blockIdx.y;
    if (job == 5) {   // x [B][384][4096] f32 -> xT [B][4096][384] bf16
        for (int i = blockIdx.x * 256 + threadIdx.x; i < BATCH * 4096 * 48;
             i += 576 * 256) {
            int b = i / (4096 * 48);
            int rem = i - b * (4096 * 48);
            int c8 = rem / 4096, s = rem - c8 * 4096;
            b16x8 pk;
            #pragma unroll
            for (int e = 0; e < 8; e++)
                pk[e] = (short)f2bf(x[((size_t)b * CCH + c8 * 8 + e) * NQ + s]);
            *(b16x8*)(xT + ((size_t)b * NQ + s) * CCH + c8 * 8) = pk;
        }
        return;
    }
    if (job == 3) {   // WsrB[o][ (r&3)*384 + (r>>2) ] = Wsr[o][r],  r = c*4+p
        for (int i = blockIdx.x * 256 + threadIdx.x; i < 589824; i += gridDim.x * 256) {
            int o = i / 1536, r = i - o * 1536;
            WsrB[o * 1536 + (r & 3) * 384 + (r >> 2)] = (short)f2bf(Wsr[i]);
        }
        return;
    }
    const float* src; short* dst;
    if (job == 0)      { src = Wq;  dst = WqB; }
    else if (job == 1) { src = Wk;  dst = WkvB; }
    else if (job == 2) { src = Wv;  dst = WkvB + 147456; }
    else               { src = Wp;  dst = WpB; }
    for (int i = blockIdx.x * 256 + threadIdx.x; i < 147456; i += gridDim.x * 256)
        dst[i] = (short)f2bf(src[i]);
}

// ---------------------------------------------------------------------------
// FUSED conv+Q GEMM (480 blocks).  id<24 per batch: SR-conv (im2col, K=1536,
// +bsr) -> xsrT.  Else: Q (K=384) -> qT.
// ---------------------------------------------------------------------------
__global__ __launch_bounds__(256, 2) void fused_gemm1(
    const short* __restrict__ WsrB, const short* __restrict__ WqB,
    const short* __restrict__ xT, const float* __restrict__ bsr,
    short* __restrict__ xsrT, short* __restrict__ qTb)
{
    __shared__ short At[128 * 64];
    __shared__ short Bt[128 * 64];
    const int b = blockIdx.z;
    const int id = blockIdx.x;
    const bool conv = id < 24;
    const int sx = conv ? (id & 7) : ((id - 24) & 31);
    const int oy = conv ? (id >> 3) : ((id - 24) >> 5);
    const int Ks = conv ? 1536 : 384;
    const int S  = conv ? NK : NQ;
    const short* A = conv ? WsrB : WqB;
    short* Yt = conv ? xsrT : qTb;
    const int o0 = oy * 128, s0 = sx * 128;
    const int t = threadIdx.x, wave = t >> 6, lane = t & 63, g = lane >> 4, li = lane & 15;
    const int wr = wave >> 1, wc = wave & 1;
    floatx4 acc[4][4] = {};
    const short* Bbase = xT + (size_t)b * NQ * CCH;

    for (int k0 = 0; k0 < Ks; k0 += 64) {
        __syncthreads();
        #pragma unroll
        for (int it = 0; it < 4; it++) {
            int task = it * 256 + t;
            int row = task >> 3, ch = task & 7;
            int cont = ch ^ (row & 7);
            g2lds16(A + (size_t)(o0 + row) * Ks + k0 + cont * 8, At + task * 8);
        }
        #pragma unroll
        for (int it = 0; it < 4; it++) {
            int task = it * 256 + t;
            int row = task >> 3, ch = task & 7;
            int cont = ch ^ (row & 7);
            if (conv) {
                int ssr = s0 + row;
                int hs = ssr >> 5, wsv = ssr & 31;
                int k = k0 + cont * 8;
                int p = k / 384, coff = k - p * 384;
                g2lds16(Bbase + (size_t)((2 * hs + (p >> 1)) * 64 + 2 * wsv + (p & 1)) * 384 + coff,
                        Bt + task * 8);
            } else {
                g2lds16(Bbase + (size_t)(s0 + row) * 384 + k0 + cont * 8, Bt + task * 8);
            }
        }
        __syncthreads();
        #pragma unroll
        for (int kk = 0; kk < 2; kk++) {
            b16x8 af[4], bf[4];
            #pragma unroll
            for (int mi = 0; mi < 4; mi++) {
                int r = wr * 64 + mi * 16 + li;
                af[mi] = *(const b16x8*)(At + r * 64 + (((kk * 4 + g) ^ (r & 7)) * 8));
            }
            #pragma unroll
            for (int nf = 0; nf < 4; nf++) {
                int r = wc * 64 + nf * 16 + li;
                bf[nf] = *(const b16x8*)(Bt + r * 64 + (((kk * 4 + g) ^ (r & 7)) * 8));
            }
            #pragma unroll
            for (int mi = 0; mi < 4; mi++)
                #pragma unroll
                for (int nf = 0; nf < 4; nf++)
                    acc[mi][nf] = __builtin_amdgcn_mfma_f32_16x16x32_bf16(af[mi], bf[nf], acc[mi][nf], 0, 0, 0);
        }
    }

    #pragma unroll
    for (int mi = 0; mi < 4; mi++) {
        #pragma unroll
        for (int nf = 0; nf < 4; nf++) {
            int o = o0 + wr * 64 + mi * 16 + g * 4;
            int s = s0 + wc * 64 + nf * 16 + li;
            b16x4 pk;
            #pragma unroll
            for (int j = 0; j < 4; j++) {
                float v = acc[mi][nf][j];
                if (conv) v += bsr[o + j];
                pk[j] = (short)f2bf(v);
            }
            *(b16x4*)(Yt + ((size_t)b * S + s) * CCH + o) = pk;
        }
    }
}

// ---------------------------------------------------------------------------
// KV GEMM (K=384, from xsrT): o<384 -> k (+pos, *SCALE_L2E) -> kT[m][c];
// o>=384 -> v -> vC[c][m] channel-major.
// ---------------------------------------------------------------------------
__global__ __launch_bounds__(256, 2) void kv_gemm(
    const short* __restrict__ WkvB, const short* __restrict__ xsrT,
    const float* __restrict__ relh, const float* __restrict__ relw,
    short* __restrict__ kTb, short* __restrict__ vCb)
{
    __shared__ short At[128 * 64];
    __shared__ short Bt[128 * 64];
    const int b = blockIdx.z, o0 = blockIdx.y * 128, s0 = blockIdx.x * 128;
    const int t = threadIdx.x, wave = t >> 6, lane = t & 63, g = lane >> 4, li = lane & 15;
    const int wr = wave >> 1, wc = wave & 1;
    floatx4 acc[4][4] = {};
    const short* Bbase = xsrT + (size_t)b * NK * CCH;

    for (int k0 = 0; k0 < 384; k0 += 64) {
        __syncthreads();
        #pragma unroll
        for (int it = 0; it < 4; it++) {
            int task = it * 256 + t;
            int row = task >> 3, ch = task & 7;
            int cont = ch ^ (row & 7);
            g2lds16(WkvB + (size_t)(o0 + row) * 384 + k0 + cont * 8, At + task * 8);
        }
        #pragma unroll
        for (int it = 0; it < 4; it++) {
            int task = it * 256 + t;
            int row = task >> 3, ch = task & 7;
            int cont = ch ^ (row & 7);
            g2lds16(Bbase + (size_t)(s0 + row) * 384 + k0 + cont * 8, Bt + task * 8);
        }
        __syncthreads();
        #pragma unroll
        for (int kk = 0; kk < 2; kk++) {
            b16x8 af[4], bf[4];
            #pragma unroll
            for (int mi = 0; mi < 4; mi++) {
                int r = wr * 64 + mi * 16 + li;
                af[mi] = *(const b16x8*)(At + r * 64 + (((kk * 4 + g) ^ (r & 7)) * 8));
            }
            #pragma unroll
            for (int nf = 0; nf < 4; nf++) {
                int r = wc * 64 + nf * 16 + li;
                bf[nf] = *(const b16x8*)(Bt + r * 64 + (((kk * 4 + g) ^ (r & 7)) * 8));
            }
            #pragma unroll
            for (int mi = 0; mi < 4; mi++)
                #pragma unroll
                for (int nf = 0; nf < 4; nf++)
                    acc[mi][nf] = __builtin_amdgcn_mfma_f32_16x16x32_bf16(af[mi], bf[nf], acc[mi][nf], 0, 0, 0);
        }
    }

    #pragma unroll
    for (int mi = 0; mi < 4; mi++) {
        #pragma unroll
        for (int nf = 0; nf < 4; nf++) {
            int o = o0 + wr * 64 + mi * 16 + g * 4;
            int s = s0 + wc * 64 + nf * 16 + li;
            if (o0 < 384) {
                int hs = s >> 5, wsv = s & 31;
                b16x4 pk;
                #pragma unroll
                for (int j = 0; j < 4; j++)
                    pk[j] = (short)f2bf((acc[mi][nf][j] + relh[(o + j) * 32 + wsv]
                                         + relw[(o + j) * 32 + hs]) * SCALE_L2E);
                *(b16x4*)(kTb + ((size_t)b * NK + s) * CCH + o) = pk;
            } else {
                #pragma unroll
                for (int j = 0; j < 4; j++)
                    vCb[((size_t)b * CCH + (o - 384 + j)) * NK + s] = (short)f2bf(acc[mi][nf][j]);
            }
        }
    }
}

// ---------------------------------------------------------------------------
// P projection GEMM: out[o][s] f32 = sum_k Wp[o][k] * attT[s][k] + bp[o].
// ---------------------------------------------------------------------------
__global__ __launch_bounds__(256, 2) void p_gemm(
    const short* __restrict__ A, const short* __restrict__ Bm,
    float* __restrict__ Yf, const float* __restrict__ bias)
{
    __shared__ short At[128 * 64];
    __shared__ short Bt[128 * 64];
    const int b = blockIdx.z, o0 = blockIdx.y * 128, s0 = blockIdx.x * 128;
    const int t = threadIdx.x, wave = t >> 6, lane = t & 63, g = lane >> 4, li = lane & 15;
    const int wr = wave >> 1, wc = wave & 1;
    floatx4 acc[4][4] = {};
    const short* Bbase = Bm + (size_t)b * NQ * CCH;

    for (int k0 = 0; k0 < 384; k0 += 64) {
        __syncthreads();
        #pragma unroll
        for (int it = 0; it < 4; it++) {
            int task = it * 256 + t;
            int row = task >> 3, ch = task & 7;
            int cont = ch ^ (row & 7);
            g2lds16(A + (size_t)(o0 + row) * 384 + k0 + cont * 8, At + task * 8);
        }
        #pragma unroll
        for (int it = 0; it < 4; it++) {
            int task = it * 256 + t;
            int row = task >> 3, ch = task & 7;
            int cont = ch ^ (row & 7);
            g2lds16(Bbase + (size_t)(s0 + row) * 384 + k0 + cont * 8, Bt + task * 8);
        }
        __syncthreads();
        #pragma unroll
        for (int kk = 0; kk < 2; kk++) {
            b16x8 af[4], bf[4];
            #pragma unroll
            for (int mi = 0; mi < 4; mi++) {
                int r = wr * 64 + mi * 16 + li;
                af[mi] = *(const b16x8*)(At + r * 64 + (((kk * 4 + g) ^ (r & 7)) * 8));
            }
            #pragma unroll
            for (int nf = 0; nf < 4; nf++) {
                int r = wc * 64 + nf * 16 + li;
                bf[nf] = *(const b16x8*)(Bt + r * 64 + (((kk * 4 + g) ^ (r & 7)) * 8));
            }
            #pragma unroll
            for (int mi = 0; mi < 4; mi++)
                #pragma unroll
                for (int nf = 0; nf < 4; nf++)
                    acc[mi][nf] = __builtin_amdgcn_mfma_f32_16x16x32_bf16(af[mi], bf[nf], acc[mi][nf], 0, 0, 0);
        }
    }

    #pragma unroll
    for (int mi = 0; mi < 4; mi++) {
        #pragma unroll
        for (int nf = 0; nf < 4; nf++) {
            int o = o0 + wr * 64 + mi * 16 + g * 4;
            int s = s0 + wc * 64 + nf * 16 + li;
            #pragma unroll
            for (int j = 0; j < 4; j++)
                Yf[((size_t)b * CCH + o + j) * (size_t)NQ + s] = acc[mi][nf][j] + bias[o + j];
        }
    }
}

// ---------------------------------------------------------------------------
// Flash attention v11c: 8 waves x QBLK32 = 256 q/block, 512 blocks (exactly
// 2 blocks/CU) -> 4 waves/SIMD.  Counted-vmcnt 3-buffer pipeline.
// FIX vs rounds 18/19: V LDS destination is LANE-LINEAR per instruction
// (row = lane, exec-masked lane<48), per rule #21 — the vtask/48 mapping
// broke lane-linearity and clobbered the pad/ones rows (NaN).
// Staging: waves 0-5 = K (1 load, chunk = wave, dst = t*16B lane-linear);
// waves 6-7 = V (4 chunk-loads each, dst = chunk base + lane*16B).
// ---------------------------------------------------------------------------
__global__ __launch_bounds__(512, 4) void attn_kern(
    const short* __restrict__ qT, const short* __restrict__ kT,
    const short* __restrict__ vC, short* __restrict__ attT)
{
    __shared__ short SH[3 * 3072 + 3 * 4096];      // 42 KB: Kl[3]@0, Vl[3]@9216
    short* const Klb = SH;                         // Kl[b] = SH + b*3072
    short* const Vlb = SH + 3 * 3072;              // Vl[b] = SH + 9216 + b*4096
    const int wgid = blockIdx.x;
    const int nid = (wgid & 7) * 64 + (wgid >> 3);     // XCD swizzle (512 = 8*64)
    const int qt = nid & 15, hh = (nid >> 4) & 7, b = nid >> 7;
    const int t = threadIdx.x, wave = t >> 6, lane = t & 63;
    const int h = lane >> 5, c = lane & 31;
    const int n0 = qt * 256 + wave * 32;

    const short* qp = qT + (size_t)b * NQ * CCH + hh * HDIM;
    const short* kp = kT + (size_t)b * NK * CCH + hh * HDIM;
    const short* vp = vC + ((size_t)b * CCH + hh * HDIM) * NK;

    // init V pad rows 48..63 of all 3 buffers: row 48 = 1.0 (l-col), rest 0
    if (t < 384) {                                // 3 bufs x 8 chunks x 16 rows
        int bufi = t >> 7, rem = t & 127;
        int ch = rem >> 4, row = 48 + (rem & 15);
        b16x8 val = {};
        if (row == 48)
            #pragma unroll
            for (int e = 0; e < 8; e++) val[e] = (short)0x3F80;
        *(b16x8*)(Vlb + bufi * 4096 + (ch * 64 + row) * 8) = val;
    }
    asm volatile("s_waitcnt lgkmcnt(0)" ::: "memory");  // own pad writes retired

    // Q B-frags (persist): lane holds q = c, d = dc*16 + h*8 + e
    b16x8 qf[3];
    #pragma unroll
    for (int dc = 0; dc < 3; dc++)
        qf[dc] = *(const b16x8*)(qp + (size_t)(n0 + c) * CCH + dc * 16 + h * 8);
    asm volatile("s_waitcnt vmcnt(0)" ::: "memory");    // qf resident; clean counter

    // staging geometry (tile-invariant), 512 threads:
    //  K: waves 0-5: 1 load; chunk = wave, key row = lane (permuted source),
    //     dst = t*16B  (lane-linear from wave base)                     [ok]
    //  V: waves 6-7: 4 chunk-loads; row = lane, exec-mask lane<48,
    //     dst = (chunk*64 + lane)*16B (lane-linear from chunk base)     [ok]
    const bool isK = t < 384;
    const int krow = lane;
    const int keyS = (krow & 51) | ((krow & 4) << 1) | ((krow & 8) >> 1);
    const short* ksrc = kp + (size_t)keyS * CCH + wave * 8;   // wave==chunk (0..5)
    const int kdst8 = t * 8;
    const int vch0 = (wave - 6) * 4;               // 0 or 4 (V waves only)
    const short* vrowsrc = vp + (size_t)lane * NK; // row = lane (masked lane<48)

    auto stage = [&](int m0, int bi) {
        if (isK) {
            g2lds16(ksrc + (size_t)m0 * CCH, Klb + bi * 3072 + kdst8);   // 1 load
        } else if (lane < 48) {
            short* vb = Vlb + bi * 4096;                                  // 4 loads
            #pragma unroll
            for (int i = 0; i < 4; i++)
                g2lds16(vrowsrc + (vch0 + i) * 8 + m0, vb + ((vch0 + i) * 64 + lane) * 8);
        }
    };

    f32x16 O[2] = {};          // [dblock];  O[1] col c=16 accumulates l

    stage(0, 0);
    stage(64, 1);
    int cur = 0;
    for (int tt = 0; tt < 16; ++tt) {
        // wait for tile tt's loads only (tile tt+1's stay in flight)
        if (tt < 15) {
            if (isK) asm volatile("s_waitcnt vmcnt(1)" ::: "memory");
            else     asm volatile("s_waitcnt vmcnt(4)" ::: "memory");
        } else {
            asm volatile("s_waitcnt vmcnt(0)" ::: "memory");
        }
        __builtin_amdgcn_s_barrier();
        const short* Kb = Klb + cur * 3072;
        const short* Vb = Vlb + cur * 4096;
        #pragma unroll
        for (int kb = 0; kb < 2; kb++) {
            b16x8 kf[3];
            #pragma unroll
            for (int dc = 0; dc < 3; dc++)
                kf[dc] = *(const b16x8*)(Kb + (((dc * 2 + h) * 64) + kb * 32 + c) * 8);
            f32x16 s = {};
            __builtin_amdgcn_s_setprio(1);
            #pragma unroll
            for (int dc = 0; dc < 3; dc++)
                s = __builtin_amdgcn_mfma_f32_32x32x16_bf16(kf[dc], qf[dc], s, 0, 0, 0);
            __builtin_amdgcn_s_setprio(0);
            float p[16];
            #pragma unroll
            for (int r = 0; r < 16; r++)
                p[r] = __builtin_amdgcn_exp2f(s[r]);
            b16x8 pfrag[2];
            #pragma unroll
            for (int kk = 0; kk < 2; kk++) {
                union { unsigned u[4]; b16x8 v; } w;
                #pragma unroll
                for (int wd = 0; wd < 4; wd++)
                    asm("v_cvt_pk_bf16_f32 %0, %1, %2"
                        : "=v"(w.u[wd])
                        : "v"(p[kk * 8 + wd * 2]), "v"(p[kk * 8 + wd * 2 + 1]));
                pfrag[kk] = w.v;
            }
            __builtin_amdgcn_s_setprio(1);
            #pragma unroll
            for (int kk = 0; kk < 2; kk++)
                #pragma unroll
                for (int db = 0; db < 2; db++) {
                    b16x8 vf = *(const b16x8*)(Vb + (((kb * 4 + kk * 2 + h) * 64) + db * 32 + c) * 8);
                    O[db] = __builtin_amdgcn_mfma_f32_32x32x16_bf16(pfrag[kk], vf, O[db], 0, 0, 0);
                }
            __builtin_amdgcn_s_setprio(0);
        }
        // prefetch tile tt+2 into buffer (cur+2)%3 (safe: all waves passed
        // barrier tt -> finished reading buf (tt-1)%3 == (cur+2)%3)
        if (tt < 14) {
            int nb = cur + 2; if (nb >= 3) nb -= 3;
            stage((tt + 2) * 64, nb);
        }
        cur = (cur == 2) ? 0 : cur + 1;
    }

    __syncthreads();   // full drain: all waves done reading V before overlay
    // l[q-slot r] lives in lane (h, c=16) at O[1][r]; wave-private bounce
    short* Olw = SH + wave * 2048;   // 8 waves x 4 KB = 32 KB <= 42 KB (in-bounds)
    #pragma unroll
    for (int r = 0; r < 16; r++) {
        int qrow = (r & 3) + 8 * (r >> 2) + 4 * h;
        float lr = __shfl(O[1][r], (lane & 32) | 16);
        float iq = 1.0f / lr;
        #pragma unroll
        for (int db = 0; db < 2; db++) {
            int d = db * 32 + c;
            if (d < 48)
                Olw[qrow * 64 + (((d >> 3) ^ (qrow & 7)) * 8) + (d & 7)] =
                    (short)f2bf(O[db][r] * iq);
        }
    }
    // DS ops in-order per wave; Olw wave-private -> no barrier needed
    #pragma unroll
    for (int it = 0; it < 4; it++) {
        int idx = it * 64 + lane;
        int row = idx >> 3, c8 = idx & 7;
        if (c8 < 6) {
            b16x8 val = *(const b16x8*)(Olw + row * 64 + ((c8 ^ (row & 7)) * 8));
            *(b16x8*)(attT + ((size_t)b * NQ + n0 + row) * CCH + hh * HDIM + c8 * 8) = val;
        }
    }
}

// ---------------------------------------------------------------------------
extern "C" void kernel_launch(void* const* d_in, const int* in_sizes, int n_in,
                              void* d_out, int out_size, void* d_ws, size_t ws_size,
                              hipStream_t stream) {
    const float* x    = (const float*)d_in[0];
    const float* Wq   = (const float*)d_in[1];
    const float* Wk   = (const float*)d_in[2];
    const float* Wv   = (const float*)d_in[3];
    const float* Wsr  = (const float*)d_in[4];
    const float* bsr  = (const float*)d_in[5];
    const float* Wp   = (const float*)d_in[6];
    const float* bp   = (const float*)d_in[7];
    const float* relh = (const float*)d_in[8];
    const float* relw = (const float*)d_in[9];
    float* out = (float*)d_out;

    short* ws = (short*)d_ws;
    size_t off = 0;
    auto alloc = [&](size_t n) { short* p = ws + off; off += n; return p; };
    short* WqB  = alloc(147456);
    short* WkvB = alloc(294912);
    short* WsrB = alloc(589824);
    short* WpB  = alloc(147456);
    short* xT   = alloc((size_t)BATCH * NQ * CCH);
    short* xsrT = alloc((size_t)BATCH * NK * CCH);
    short* qTb  = alloc((size_t)BATCH * NQ * CCH);
    short* kTb  = alloc((size_t)BATCH * NK * CCH);
    short* vCb  = alloc((size_t)BATCH * CCH * NK);
    short* attT = alloc((size_t)BATCH * NQ * CCH);

    prep_kern<<<dim3(576, 6), 256, 0, stream>>>(Wq, Wk, Wv, Wsr, Wp, x,
                                                WqB, WkvB, WsrB, WpB, xT);
    fused_gemm1<<<dim3(120, 1, BATCH), 256, 0, stream>>>(WsrB, WqB, xT, bsr, xsrT, qTb);
    kv_gemm<<<dim3(8, 6, BATCH), 256, 0, stream>>>(WkvB, xsrT, relh, relw, kTb, vCb);
    attn_kern<<<dim3(512), 512, 0, stream>>>(qTb, kTb, vCb, attT);
    p_gemm<<<dim3(32, 3, BATCH), 256, 0, stream>>>(WpB, attT, out, bp);
}